// Round 2
// 320.511 us; speedup vs baseline: 1.0140x; 1.0140x over previous
//
#include <hip/hip_runtime.h>
#include <hip/hip_bf16.h>

#define kB 16
#define kS 2048
#define kD 1024
#define kH 128
#define kBS (kB * kS)

typedef short s8v __attribute__((ext_vector_type(8)));
typedef float f4v __attribute__((ext_vector_type(4)));
typedef float f16v __attribute__((ext_vector_type(16)));
typedef unsigned short us4 __attribute__((ext_vector_type(4)));
typedef unsigned short us8 __attribute__((ext_vector_type(8)));

__device__ __forceinline__ unsigned short f2bf(float f) {
    __hip_bfloat16 h = __float2bfloat16(f);
    return __builtin_bit_cast(unsigned short, h);
}

// ---------------------------------------------------------------------------
// Kernel 0: W[1024][128] fp32 -> Wt[384][1024] bf16 (transposed, q|k|v).
// Wq pre-scaled by H^-0.5.  (unchanged)
// ---------------------------------------------------------------------------
__global__ void prep_w(const float* __restrict__ Wq, const float* __restrict__ Wk,
                       const float* __restrict__ Wv, unsigned short* __restrict__ Wt)
{
    const int g = blockIdx.x;
    const float* W = (g == 0) ? Wq : (g == 1) ? Wk : Wv;
    const float sc = (g == 0) ? 0.08838834764831845f : 1.0f;  // 128^-0.5 folded into Wq
    unsigned short* o = Wt + (size_t)g * 128 * 1024;
    const int t = threadIdx.x;
    const int n = t & 127;
    const int half = t >> 7;
    const int kbase = blockIdx.y * 64 + half * 32;
    #pragma unroll
    for (int c = 0; c < 4; ++c) {
        int kb = kbase + c * 8;
        us8 v;
        #pragma unroll
        for (int j = 0; j < 8; ++j) v[j] = f2bf(W[(size_t)(kb + j) * kH + n] * sc);
        *(us8*)(o + (size_t)n * 1024 + kb) = v;
    }
}

// ---------------------------------------------------------------------------
// Kernel 1 (R6): fused QKV GEMM.
//  - 512 threads / block (8 waves x 48 cols, acc[4][3] = 48 regs/wave)
//    -> 16 waves/CU (4/SIMD). 2 blocks/CU, all 512 blocks resident.
//  - Lane-contiguous X staging: thread t loads float4 at row (t>>5)+u*16,
//    col (t&31)*4 -> each wave instr = two full 512B row segments.
//  - Register double-buffer (issue-early/write-late): tile k+1's loads are
//    issued right after the post-pack barrier and fly under tile k's MFMA.
//  X read ONCE; Wt from L2; q,k written [s][h]; v written transposed [b][h][s].
// ---------------------------------------------------------------------------
#define PREFETCH(xv_, kn_) do {                                               \
    _Pragma("unroll")                                                         \
    for (int u = 0; u < 4; ++u)                                               \
        xv_[u] = *(const float4*)(Xp + (kn_) + (size_t)u * 16 * kD);          \
} while (0)

#define PACK_STORE(xv_) do {                                                  \
    _Pragma("unroll")                                                         \
    for (int u = 0; u < 4; ++u) {                                             \
        us4 pk = { f2bf(xv_[u].x), f2bf(xv_[u].y),                            \
                   f2bf(xv_[u].z), f2bf(xv_[u].w) };                          \
        *(us4*)&smem[(srow + u * 16) * 136 + scol] = pk;                      \
    }                                                                         \
} while (0)

#define COMPUTE_TILE(k0_) do {                                                \
    _Pragma("unroll")                                                         \
    for (int ks = 0; ks < 4; ++ks) {                                          \
        s8v Af[4], Bf[3];                                                     \
        _Pragma("unroll")                                                     \
        for (int i = 0; i < 4; ++i)                                           \
            Af[i] = *(const s8v*)&smem[(i * 16 + col) * 136 + ks * 32 + quad * 8]; \
        _Pragma("unroll")                                                     \
        for (int j = 0; j < 3; ++j)                                           \
            Bf[j] = *(const s8v*)(Wt + (size_t)(w * 48 + j * 16 + col) * kD   \
                                  + (k0_) + ks * 32 + quad * 8);              \
        _Pragma("unroll")                                                     \
        for (int i = 0; i < 4; ++i)                                           \
            _Pragma("unroll")                                                 \
            for (int j = 0; j < 3; ++j)                                       \
                acc[i][j] = __builtin_amdgcn_mfma_f32_16x16x32_bf16(          \
                    Af[i], Bf[j], acc[i][j], 0, 0, 0);                        \
    }                                                                         \
} while (0)

__global__ __launch_bounds__(512, 4) void qkv_gemm(
    const float* __restrict__ X, const unsigned short* __restrict__ Wt,
    unsigned short* __restrict__ ws)
{
    __shared__ unsigned short smem[9216];   // Xs[64][136] bf16 | epilogue repack

    const int t    = threadIdx.x;
    const int L    = t & 63;
    const int w    = t >> 6;                 // wave 0..7, owns cols w*48..w*48+47
    const int col  = L & 15;
    const int quad = L >> 4;
    const int m0   = blockIdx.x * 64;

    f4v acc[4][3];
    #pragma unroll
    for (int i = 0; i < 4; ++i)
        #pragma unroll
        for (int j = 0; j < 3; ++j) { f4v z = {0.f, 0.f, 0.f, 0.f}; acc[i][j] = z; }

    const int srow = t >> 5;                 // 0..15
    const int scol = (t & 31) * 4;           // float col 0..124 within K-slice
    const float* Xp = X + (size_t)(m0 + srow) * kD + scol;

    float4 xa[4], xb[4];
    PREFETCH(xa, 0);

    #pragma unroll
    for (int kp = 0; kp < 4; ++kp) {         // two K-tiles (128 each) per pair
        const int ke = kp * 256;
        __syncthreads();                     // previous compute done reading smem
        PACK_STORE(xa);                      // (waits xa's vmcnt)
        __syncthreads();
        PREFETCH(xb, ke + 128);              // fly under the MFMA below
        COMPUTE_TILE(ke);
        __syncthreads();
        PACK_STORE(xb);
        __syncthreads();
        if (kp < 3) PREFETCH(xa, ke + 256);
        COMPUTE_TILE(ke + 128);
    }

    // ---- epilogue: repack via LDS, write q/k [s][h] and v^T [b][h][s] ----
    for (int g = 0; g < 3; ++g) {
        __syncthreads();
        #pragma unroll
        for (int j = 0; j < 3; ++j) {
            if (((48 * w + 16 * j) >> 7) != g) continue;   // wave-uniform
            int n = w * 48 + j * 16 + col;
            if (g < 2) {
                int ng = n - g * 128;
                #pragma unroll
                for (int i = 0; i < 4; ++i)
                    #pragma unroll
                    for (int rg = 0; rg < 4; ++rg)
                        smem[(i * 16 + quad * 4 + rg) * 136 + ng] = f2bf(acc[i][j][rg]);
            } else {
                int h = n - 256;
                #pragma unroll
                for (int i = 0; i < 4; ++i) {
                    us4 pk = { f2bf(acc[i][j][0]), f2bf(acc[i][j][1]),
                               f2bf(acc[i][j][2]), f2bf(acc[i][j][3]) };
                    *(us4*)&smem[h * 72 + i * 16 + quad * 4] = pk;   // Ts[h][s]
                }
            }
        }
        __syncthreads();
        if (g < 2) {
            unsigned short* outp = ws + (size_t)g * kBS * kH;
            int row = t >> 3, hc = (t & 7) * 16;
            #pragma unroll
            for (int u = 0; u < 2; ++u) {
                us8 v = *(const us8*)&smem[row * 136 + hc + u * 8];
                *(us8*)(outp + (size_t)(m0 + row) * kH + hc + u * 8) = v;
            }
        } else {
            unsigned short* vtp = ws + (size_t)2 * kBS * kH;
            int h0 = t >> 4, sc = (t & 15) * 4;
            int bb = m0 >> 11, sl = m0 & 2047;
            #pragma unroll
            for (int u = 0; u < 4; ++u) {
                int h = h0 + u * 32;
                us4 v = *(const us4*)&smem[h * 72 + sc];
                *(us4*)(vtp + ((size_t)bb * kH + h) * kS + sl + sc) = v;
            }
        }
    }
}

// ---------------------------------------------------------------------------
// Kernel 2: causal attention — fully WAVE-LOCAL (unchanged from R5). One
// 64-lane wave owns one 32-row q-slot and iterates ALL its key tiles.
// ---------------------------------------------------------------------------
__global__ __launch_bounds__(64, 1) void attn(
    const unsigned short* __restrict__ ws, float* __restrict__ out)
{
    __shared__ unsigned short Ps[32 * 36];   // P[q][key], stride 36 (2-way bank only)

    const int L   = threadIdx.x;             // 0..63
    const int l5  = L >> 5;
    const int c32 = L & 31;
    const int b   = blockIdx.x;
    const int g2  = blockIdx.y >> 4, ii = blockIdx.y & 15;
    const int s   = (g2 == 0) ? 63 - ii : (g2 == 1) ? 32 + ii
                  : (g2 == 2) ? 31 - ii : ii;          // bijective onto 0..63

    const unsigned short* qp = ws;
    const unsigned short* kp = ws + (size_t)kBS * kH + (size_t)b * kS * kH;
    const unsigned short* vt = ws + (size_t)2 * kBS * kH + (size_t)b * kH * kS;

    const size_t qrow = (size_t)b * kS + s * 32 + c32;

    // Q B-frags (B-layout: n=lane&31 -> q=c32, k=l5*8+j at k-offset ks*16)
    s8v Qf[8];
    #pragma unroll
    for (int ks = 0; ks < 8; ++ks)
        Qf[ks] = *(const s8v*)(qp + qrow * kH + ks * 16 + l5 * 8);

    f16v O[4];
    #pragma unroll
    for (int nt = 0; nt < 4; ++nt)
        #pragma unroll
        for (int r = 0; r < 16; ++r) O[nt][r] = 0.f;
    float lsum = 0.f;

    // prefetch K tile 0 (A-layout: m=lane&31 -> key row, k=l5*8+j)
    s8v Kf[8];
    #pragma unroll
    for (int ks = 0; ks < 8; ++ks)
        Kf[ks] = *(const s8v*)(kp + (size_t)c32 * kH + ks * 16 + l5 * 8);

    for (int T = 0; T <= s; ++T) {
        const int kb = T * 32;
        // V^T A-frags (m = h within 32-group = c32, k = key)
        s8v Vf[2][4];
        #pragma unroll
        for (int k2 = 0; k2 < 2; ++k2)
            #pragma unroll
            for (int nt = 0; nt < 4; ++nt)
                Vf[k2][nt] = *(const s8v*)(vt + (size_t)(nt * 32 + c32) * kS
                                           + kb + k2 * 16 + l5 * 8);
        // S^T = K Q^T
        f16v Sv;
        #pragma unroll
        for (int r = 0; r < 16; ++r) Sv[r] = 0.f;
        #pragma unroll
        for (int ks = 0; ks < 8; ++ks)
            Sv = __builtin_amdgcn_mfma_f32_32x32x16_bf16(Kf[ks], Qf[ks], Sv, 0, 0, 0);
        // prefetch next K tile
        if (T < s) {
            #pragma unroll
            for (int ks = 0; ks < 8; ++ks)
                Kf[ks] = *(const s8v*)(kp + (size_t)(kb + 32 + c32) * kH + ks * 16 + l5 * 8);
        }
        // mask (diagonal tile) + exp + P store; lane holds 16 keys of q=c32
        const bool dm = (T == s);
        #pragma unroll
        for (int g4 = 0; g4 < 4; ++g4) {
            us4 pk;
            #pragma unroll
            for (int u = 0; u < 4; ++u) {
                int krow = u + 8 * g4 + 4 * l5;       // C-layout row = key
                float v = Sv[g4 * 4 + u];
                if (dm && krow > c32) v = -__builtin_inff();
                float e = __expf(v);
                lsum += e;
                pk[u] = f2bf(e);
            }
            *(us4*)&Ps[c32 * 36 + 8 * g4 + 4 * l5] = pk;
        }
        // O^T += V^T P^T (same-wave LDS roundtrip)
        #pragma unroll
        for (int k2 = 0; k2 < 2; ++k2) {
            us4 plo = *(const us4*)&Ps[c32 * 36 + k2 * 16 + l5 * 8];
            us4 phi = *(const us4*)&Ps[c32 * 36 + k2 * 16 + l5 * 8 + 4];
            us8 pc;
            pc[0]=plo[0]; pc[1]=plo[1]; pc[2]=plo[2]; pc[3]=plo[3];
            pc[4]=phi[0]; pc[5]=phi[1]; pc[6]=phi[2]; pc[7]=phi[3];
            s8v Pb = __builtin_bit_cast(s8v, pc);
            #pragma unroll
            for (int nt = 0; nt < 4; ++nt)
                O[nt] = __builtin_amdgcn_mfma_f32_32x32x16_bf16(Vf[k2][nt], Pb, O[nt], 0, 0, 0);
        }
    }

    // total l for q=c32: combine the two l5 half-sums in-wave
    float lv = lsum + __shfl_xor(lsum, 32);
    const float inv = 1.0f / lv;

    // write out: h = nt*32 + 8*g4 + 4*l5 + u, q = c32
    #pragma unroll
    for (int nt = 0; nt < 4; ++nt)
        #pragma unroll
        for (int g4 = 0; g4 < 4; ++g4) {
            f4v r;
            #pragma unroll
            for (int u = 0; u < 4; ++u) r[u] = O[nt][g4 * 4 + u] * inv;
            *(f4v*)(out + qrow * kH + nt * 32 + 8 * g4 + 4 * l5) = r;
        }
}

extern "C" void kernel_launch(void* const* d_in, const int* in_sizes, int n_in,
                              void* d_out, int out_size, void* d_ws, size_t ws_size,
                              hipStream_t stream) {
    const float* X  = (const float*)d_in[0];
    const float* Wq = (const float*)d_in[1];
    const float* Wk = (const float*)d_in[2];
    const float* Wv = (const float*)d_in[3];
    unsigned short* ws = (unsigned short*)d_ws;          // q | k | v^T bf16 (25.2 MB)
    unsigned short* Wt = ws + (size_t)3 * kBS * kH;      // +768 KB transposed weights
    float* out = (float*)d_out;

    prep_w<<<dim3(3, 16), 256, 0, stream>>>(Wq, Wk, Wv, Wt);
    qkv_gemm<<<dim3(kBS / 64), 512, 0, stream>>>(X, Wt, ws);
    attn<<<dim3(kB, 64), 64, 0, stream>>>(ws, out);
}

// Round 3
// 318.855 us; speedup vs baseline: 1.0192x; 1.0052x over previous
//
#include <hip/hip_runtime.h>
#include <hip/hip_bf16.h>

#define kB 16
#define kS 2048
#define kD 1024
#define kH 128
#define kBS (kB * kS)

typedef short s8v __attribute__((ext_vector_type(8)));
typedef float f4v __attribute__((ext_vector_type(4)));
typedef float f16v __attribute__((ext_vector_type(16)));
typedef unsigned short us4 __attribute__((ext_vector_type(4)));
typedef unsigned short us8 __attribute__((ext_vector_type(8)));

__device__ __forceinline__ unsigned short f2bf(float f) {
    __hip_bfloat16 h = __float2bfloat16(f);
    return __builtin_bit_cast(unsigned short, h);
}

// ---------------------------------------------------------------------------
// Kernel 0: W[1024][128] fp32 -> Wt[384][1024] bf16 (transposed, q|k|v).
// Wq pre-scaled by H^-0.5.  (unchanged)
// ---------------------------------------------------------------------------
__global__ void prep_w(const float* __restrict__ Wq, const float* __restrict__ Wk,
                       const float* __restrict__ Wv, unsigned short* __restrict__ Wt)
{
    const int g = blockIdx.x;
    const float* W = (g == 0) ? Wq : (g == 1) ? Wk : Wv;
    const float sc = (g == 0) ? 0.08838834764831845f : 1.0f;  // 128^-0.5 folded into Wq
    unsigned short* o = Wt + (size_t)g * 128 * 1024;
    const int t = threadIdx.x;
    const int n = t & 127;
    const int half = t >> 7;
    const int kbase = blockIdx.y * 64 + half * 32;
    #pragma unroll
    for (int c = 0; c < 4; ++c) {
        int kb = kbase + c * 8;
        us8 v;
        #pragma unroll
        for (int j = 0; j < 8; ++j) v[j] = f2bf(W[(size_t)(kb + j) * kH + n] * sc);
        *(us8*)(o + (size_t)n * 1024 + kb) = v;
    }
}

// ---------------------------------------------------------------------------
// Kernel 1 (R7): fused QKV GEMM — BOTH operands staged in LDS.
//  Theory: R0/R6 both stalled ~85% with B (Wt) fragments loaded from L2
//  INSIDE the MFMA loop (16-line scatter per instr); occupancy-independent
//  => saturated TA/TCP request path. Fix: stage Bs[384][40] per K-step with
//  line-coalesced loads; LDS double-buffer; ONE barrier per K-step; regs
//  prefetch K-step t+2 under MFMA of t.
//  Tile 64m x 384n, BK=32, 4 waves, acc[4][6]. X read once. 512 blocks.
// ---------------------------------------------------------------------------
#define LOAD_AB(t_) do {                                                      \
    const int k0_ = (t_) * 32;                                                \
    av[0] = *(const float4*)(Xp + k0_);                                       \
    av[1] = *(const float4*)(Xp + k0_ + 4);                                   \
    _Pragma("unroll")                                                         \
    for (int p = 0; p < 6; ++p)                                               \
        bv[p] = *(const us8*)(Wp + (size_t)p * 64 * kD + k0_);                \
} while (0)

#define CVT_WRITE(b_) do {                                                    \
    us8 aw;                                                                   \
    aw[0] = f2bf(av[0].x); aw[1] = f2bf(av[0].y);                             \
    aw[2] = f2bf(av[0].z); aw[3] = f2bf(av[0].w);                             \
    aw[4] = f2bf(av[1].x); aw[5] = f2bf(av[1].y);                             \
    aw[6] = f2bf(av[1].z); aw[7] = f2bf(av[1].w);                             \
    *(us8*)&smem[(b_) * 17920 + arow * 40 + ac8] = aw;                        \
    _Pragma("unroll")                                                         \
    for (int p = 0; p < 6; ++p)                                               \
        *(us8*)&smem[(b_) * 17920 + 2560 + (p * 64 + arow) * 40 + ac8] = bv[p]; \
} while (0)

__global__ __launch_bounds__(256, 2) void qkv_gemm(
    const float* __restrict__ X, const unsigned short* __restrict__ Wt,
    unsigned short* __restrict__ ws)
{
    // buf b: As[64][40] at b*17920, Bs[384][40] at b*17920+2560 (shorts).
    // Epilogue reuses the same space (Cs[64][136] / Ct[128][72]).
    __shared__ unsigned short smem[35840];

    const int t    = threadIdx.x;
    const int L    = t & 63;
    const int w    = t >> 6;                 // wave 0..3, owns cols w*96..w*96+95
    const int col  = L & 15;
    const int quad = L >> 4;
    const int m0   = blockIdx.x * 64;

    f4v acc[4][6];
    #pragma unroll
    for (int i = 0; i < 4; ++i)
        #pragma unroll
        for (int j = 0; j < 6; ++j) { f4v z = {0.f, 0.f, 0.f, 0.f}; acc[i][j] = z; }

    const int arow = t >> 2;                 // 0..63
    const int ac8  = (t & 3) * 8;            // 0,8,16,24
    const float* Xp          = X  + (size_t)(m0 + arow) * kD + ac8;
    const unsigned short* Wp = Wt + (size_t)arow * kD + ac8;

    float4 av[2];
    us8 bv[6];

    LOAD_AB(0);
    CVT_WRITE(0);        // waits tile-0 loads, fills buf0
    LOAD_AB(1);
    __syncthreads();

    #pragma unroll 2
    for (int tt = 0; tt < 32; ++tt) {
        const int cb = (tt & 1) * 17920;
        s8v Af[4], Bf[6];
        #pragma unroll
        for (int i = 0; i < 4; ++i)
            Af[i] = *(const s8v*)&smem[cb + (i * 16 + col) * 40 + quad * 8];
        #pragma unroll
        for (int j = 0; j < 6; ++j)
            Bf[j] = *(const s8v*)&smem[cb + 2560 + (w * 96 + j * 16 + col) * 40 + quad * 8];
        #pragma unroll
        for (int i = 0; i < 4; ++i)
            #pragma unroll
            for (int j = 0; j < 6; ++j)
                acc[i][j] = __builtin_amdgcn_mfma_f32_16x16x32_bf16(
                    Af[i], Bf[j], acc[i][j], 0, 0, 0);
        if (tt < 31) CVT_WRITE((tt + 1) & 1);   // write tile tt+1 into other buf
        if (tt < 30) LOAD_AB(tt + 2);           // prefetch tile tt+2 into regs
        __syncthreads();
    }

    // ---- epilogue: repack via LDS, write q/k [s][h] and v^T [b][h][s] ----
    for (int g = 0; g < 3; ++g) {
        __syncthreads();
        #pragma unroll
        for (int j = 0; j < 6; ++j) {
            if (((96 * w + 16 * j) >> 7) != g) continue;   // wave-uniform
            int n = 96 * w + 16 * j + col;
            if (g < 2) {
                int ng = n - g * 128;
                #pragma unroll
                for (int i = 0; i < 4; ++i)
                    #pragma unroll
                    for (int rg = 0; rg < 4; ++rg)
                        smem[(i * 16 + quad * 4 + rg) * 136 + ng] = f2bf(acc[i][j][rg]);
            } else {
                int h = n - 256;
                #pragma unroll
                for (int i = 0; i < 4; ++i) {
                    us4 pk = { f2bf(acc[i][j][0]), f2bf(acc[i][j][1]),
                               f2bf(acc[i][j][2]), f2bf(acc[i][j][3]) };
                    *(us4*)&smem[h * 72 + i * 16 + quad * 4] = pk;   // Ts[h][s]
                }
            }
        }
        __syncthreads();
        if (g < 2) {
            unsigned short* outp = ws + (size_t)g * kBS * kH;
            int row = t >> 2, hc = (t & 3) * 32;
            #pragma unroll
            for (int u = 0; u < 4; ++u) {
                us8 v = *(const us8*)&smem[row * 136 + hc + u * 8];
                *(us8*)(outp + (size_t)(m0 + row) * kH + hc + u * 8) = v;
            }
        } else {
            unsigned short* vtp = ws + (size_t)2 * kBS * kH;
            int h = t >> 1, sb = (t & 1) * 32;
            int bb = m0 >> 11, sl = m0 & 2047;
            #pragma unroll
            for (int u = 0; u < 4; ++u) {
                us8 v = *(const us8*)&smem[h * 72 + sb + u * 8];
                *(us8*)(vtp + ((size_t)bb * kH + h) * kS + sl + sb + u * 8) = v;
            }
        }
    }
}

// ---------------------------------------------------------------------------
// Kernel 2: causal attention — fully WAVE-LOCAL (unchanged). One 64-lane
// wave owns one 32-row q-slot and iterates ALL its key tiles.
// ---------------------------------------------------------------------------
__global__ __launch_bounds__(64, 1) void attn(
    const unsigned short* __restrict__ ws, float* __restrict__ out)
{
    __shared__ unsigned short Ps[32 * 36];   // P[q][key], stride 36 (2-way bank only)

    const int L   = threadIdx.x;             // 0..63
    const int l5  = L >> 5;
    const int c32 = L & 31;
    const int b   = blockIdx.x;
    const int g2  = blockIdx.y >> 4, ii = blockIdx.y & 15;
    const int s   = (g2 == 0) ? 63 - ii : (g2 == 1) ? 32 + ii
                  : (g2 == 2) ? 31 - ii : ii;          // bijective onto 0..63

    const unsigned short* qp = ws;
    const unsigned short* kp = ws + (size_t)kBS * kH + (size_t)b * kS * kH;
    const unsigned short* vt = ws + (size_t)2 * kBS * kH + (size_t)b * kH * kS;

    const size_t qrow = (size_t)b * kS + s * 32 + c32;

    // Q B-frags (B-layout: n=lane&31 -> q=c32, k=l5*8+j at k-offset ks*16)
    s8v Qf[8];
    #pragma unroll
    for (int ks = 0; ks < 8; ++ks)
        Qf[ks] = *(const s8v*)(qp + qrow * kH + ks * 16 + l5 * 8);

    f16v O[4];
    #pragma unroll
    for (int nt = 0; nt < 4; ++nt)
        #pragma unroll
        for (int r = 0; r < 16; ++r) O[nt][r] = 0.f;
    float lsum = 0.f;

    // prefetch K tile 0 (A-layout: m=lane&31 -> key row, k=l5*8+j)
    s8v Kf[8];
    #pragma unroll
    for (int ks = 0; ks < 8; ++ks)
        Kf[ks] = *(const s8v*)(kp + (size_t)c32 * kH + ks * 16 + l5 * 8);

    for (int T = 0; T <= s; ++T) {
        const int kb = T * 32;
        // V^T A-frags (m = h within 32-group = c32, k = key)
        s8v Vf[2][4];
        #pragma unroll
        for (int k2 = 0; k2 < 2; ++k2)
            #pragma unroll
            for (int nt = 0; nt < 4; ++nt)
                Vf[k2][nt] = *(const s8v*)(vt + (size_t)(nt * 32 + c32) * kS
                                           + kb + k2 * 16 + l5 * 8);
        // S^T = K Q^T
        f16v Sv;
        #pragma unroll
        for (int r = 0; r < 16; ++r) Sv[r] = 0.f;
        #pragma unroll
        for (int ks = 0; ks < 8; ++ks)
            Sv = __builtin_amdgcn_mfma_f32_32x32x16_bf16(Kf[ks], Qf[ks], Sv, 0, 0, 0);
        // prefetch next K tile
        if (T < s) {
            #pragma unroll
            for (int ks = 0; ks < 8; ++ks)
                Kf[ks] = *(const s8v*)(kp + (size_t)(kb + 32 + c32) * kH + ks * 16 + l5 * 8);
        }
        // mask (diagonal tile) + exp + P store; lane holds 16 keys of q=c32
        const bool dm = (T == s);
        #pragma unroll
        for (int g4 = 0; g4 < 4; ++g4) {
            us4 pk;
            #pragma unroll
            for (int u = 0; u < 4; ++u) {
                int krow = u + 8 * g4 + 4 * l5;       // C-layout row = key
                float v = Sv[g4 * 4 + u];
                if (dm && krow > c32) v = -__builtin_inff();
                float e = __expf(v);
                lsum += e;
                pk[u] = f2bf(e);
            }
            *(us4*)&Ps[c32 * 36 + 8 * g4 + 4 * l5] = pk;
        }
        // O^T += V^T P^T (same-wave LDS roundtrip)
        #pragma unroll
        for (int k2 = 0; k2 < 2; ++k2) {
            us4 plo = *(const us4*)&Ps[c32 * 36 + k2 * 16 + l5 * 8];
            us4 phi = *(const us4*)&Ps[c32 * 36 + k2 * 16 + l5 * 8 + 4];
            us8 pc;
            pc[0]=plo[0]; pc[1]=plo[1]; pc[2]=plo[2]; pc[3]=plo[3];
            pc[4]=phi[0]; pc[5]=phi[1]; pc[6]=phi[2]; pc[7]=phi[3];
            s8v Pb = __builtin_bit_cast(s8v, pc);
            #pragma unroll
            for (int nt = 0; nt < 4; ++nt)
                O[nt] = __builtin_amdgcn_mfma_f32_32x32x16_bf16(Vf[k2][nt], Pb, O[nt], 0, 0, 0);
        }
    }

    // total l for q=c32: combine the two l5 half-sums in-wave
    float lv = lsum + __shfl_xor(lsum, 32);
    const float inv = 1.0f / lv;

    // write out: h = nt*32 + 8*g4 + 4*l5 + u, q = c32
    #pragma unroll
    for (int nt = 0; nt < 4; ++nt)
        #pragma unroll
        for (int g4 = 0; g4 < 4; ++g4) {
            f4v r;
            #pragma unroll
            for (int u = 0; u < 4; ++u) r[u] = O[nt][g4 * 4 + u] * inv;
            *(f4v*)(out + qrow * kH + nt * 32 + 8 * g4 + 4 * l5) = r;
        }
}

extern "C" void kernel_launch(void* const* d_in, const int* in_sizes, int n_in,
                              void* d_out, int out_size, void* d_ws, size_t ws_size,
                              hipStream_t stream) {
    const float* X  = (const float*)d_in[0];
    const float* Wq = (const float*)d_in[1];
    const float* Wk = (const float*)d_in[2];
    const float* Wv = (const float*)d_in[3];
    unsigned short* ws = (unsigned short*)d_ws;          // q | k | v^T bf16 (25.2 MB)
    unsigned short* Wt = ws + (size_t)3 * kBS * kH;      // +768 KB transposed weights
    float* out = (float*)d_out;

    prep_w<<<dim3(3, 16), 256, 0, stream>>>(Wq, Wk, Wv, Wt);
    qkv_gemm<<<dim3(kBS / 64), 256, 0, stream>>>(X, Wt, ws);
    attn<<<dim3(kB, 64), 64, 0, stream>>>(ws, out);
}